// Round 17
// baseline (1620.434 us; speedup 1.0000x reference)
//
#include <hip/hip_runtime.h>

#define NN 50000
#define NE 800000
#define TT 2048
#define RMAXT 6.0f

__device__ __forceinline__ float siluf(float x){ return x/(1.0f+__expf(-x)); }
__device__ __forceinline__ float sigmf(float x){ return 1.0f/(1.0f+__expf(-x)); }

#define C_S 0.3826834323650898f
#define C_X 0.9238795325112867f
#define RS16 0.25f
#define RS32 0.1767766952966369f
#define RS48 0.14433756729740643f
#define RS10 0.31622776601683794f
#define SR2  0.1f
#define ISQ3 0.5773502691896258f
#define SQ3F 1.7320508075688772f
#define ISNN 0.25f
#define EMBS 2.8234621965789103f
#define PIF  3.14159265358979323846f

// LESSON (r3/5/7/8): every kernel gets __launch_bounds__(block_size).
// LESSON (r12/r15): scatter-atomic / per-thread-column LDS reduces lose;
// row-major MSG + float4 segsum sweep is the proven reduction.
// LESSON (r14): fused MLP+reduce node blocks serialize edges.
// LESSON (r16): partial unroll caps in-flight TAB loads -> VGPR 256->88,
// occupancy 2x, -17% edge time. r17: TT=2048 (TAB L2-resident) + unroll 4.

// ---------------------------------------------------------------- embed (wave per node)
__global__ void __launch_bounds__(256) k_embed(
    const float* __restrict__ oh, const float* __restrict__ W,
    const float* __restrict__ b, float* __restrict__ xs)
{
    __shared__ float lw[118*16];
    __shared__ float lb[16];
    for (int i = threadIdx.x; i < 118*16; i += blockDim.x) lw[i] = W[i];
    if (threadIdx.x < 16) lb[threadIdx.x] = b[threadIdx.x];
    __syncthreads();
    int gw = (blockIdx.x*blockDim.x + threadIdx.x) >> 6;
    int lane = threadIdx.x & 63;
    if (gw >= NN) return;
    float acc[16];
#pragma unroll
    for (int j = 0; j < 16; ++j) acc[j] = 0.f;
    for (int i = lane; i < 118; i += 64) {
        float o = oh[(size_t)gw*118 + i];
#pragma unroll
        for (int j = 0; j < 16; ++j) acc[j] += o*lw[i*16 + j];
    }
#pragma unroll
    for (int d = 32; d; d >>= 1) {
#pragma unroll
        for (int j = 0; j < 16; ++j) acc[j] += __shfl_xor(acc[j], d, 64);
    }
    if (lane == 0) {
        float* o = xs + (size_t)gw*48;
#pragma unroll
        for (int j = 0; j < 16; ++j) o[j] = acc[j] + lb[j];
    }
}

// ---------------------------------------------------------------- live classify + dst hist
__global__ void __launch_bounds__(256) k_hist2(
    const float* __restrict__ pos, const int* __restrict__ srcv,
    const int* __restrict__ dstv, int* __restrict__ cnt, int* __restrict__ livef)
{
    int e = blockIdx.x*blockDim.x + threadIdx.x;
    if (e >= NE) return;
    int s = srcv[e], d = dstv[e];
    float vx = pos[3*s+0]-pos[3*d+0], vy = pos[3*s+1]-pos[3*d+1], vz = pos[3*s+2]-pos[3*d+2];
    float r = sqrtf(vx*vx+vy*vy+vz*vz + 1e-12f);
    float tf = r*((float)(TT-1)/RMAXT);
    int lv = (tf < (float)(TT-1)) ? 1 : 0;   // r >= 6 -> filter == 0 -> edge dead
    livef[e] = lv;
    if (lv) atomicAdd(&cnt[d], 1);
}

// exclusive scan: cnt (live counts) -> start[NN+1]; cnt re-initialized to start
__global__ void __launch_bounds__(1024) k_scan(
    int* __restrict__ cnt, int* __restrict__ start)
{
    __shared__ int part[1024];
    const int L = (NN + 1023)/1024;
    int t = threadIdx.x;
    int b0 = t*L, b1 = b0 + L; if (b1 > NN) b1 = NN; if (b0 > NN) b0 = NN;
    int s = 0;
    for (int i = b0; i < b1; ++i) s += cnt[i];
    part[t] = s;
    __syncthreads();
    for (int off = 1; off < 1024; off <<= 1) {
        int vv = (t >= off) ? part[t-off] : 0;
        __syncthreads();
        part[t] += vv;
        __syncthreads();
    }
    int run = (t == 0) ? 0 : part[t-1];
    for (int i = b0; i < b1; ++i) {
        int cc = cnt[i];
        start[i] = run;
        cnt[i] = run;
        run += cc;
    }
    if (t == 1023) start[NN] = part[1023];
}

__global__ void __launch_bounds__(256) k_scatter2(
    const int* __restrict__ dstv, const int* __restrict__ livef,
    int* __restrict__ cursor, int* __restrict__ perm)
{
    int e = blockIdx.x*blockDim.x + threadIdx.x;
    if (e < NE && livef[e]) {
        int p = atomicAdd(&cursor[dstv[e]], 1);
        perm[p] = e;
    }
}

// ---------------------------------------------------------------- geometry pre-gather (live, dst-sorted, column-major)
__global__ void __launch_bounds__(256) k_geo(
    const float* __restrict__ pos, const float* __restrict__ ea,
    const int* __restrict__ srcv, const int* __restrict__ dstv,
    const int* __restrict__ perm, const int* __restrict__ startN,
    int* __restrict__ SRCg, float* __restrict__ GEO)
{
    int p = blockIdx.x*blockDim.x + threadIdx.x;
    if (p >= startN[NN]) return;
    int e = perm[p];
    int s = srcv[e], d = dstv[e];
    float vx = pos[3*s+0] - pos[3*d+0];
    float vy = pos[3*s+1] - pos[3*d+1];
    float vz = pos[3*s+2] - pos[3*d+2];
    float r  = sqrtf(vx*vx + vy*vy + vz*vz + 1e-12f);
    float ir = 1.0f/r;
    float uu = 2.0f*(r*(1.0f/3.5f) - 1.0f);
    float cut = (uu > 0.0f) ? 0.0f
              : ((uu < -1.0f) ? 1.0f : 0.5f*(1.0f - cosf(PIF*uu)));
    float cs = cut*SQ3F*ir;
    SRCg[p] = s;
    GEO[0*NE + p] = ea[3*e+0];
    GEO[1*NE + p] = ea[3*e+1];
    GEO[2*NE + p] = ea[3*e+2];
    GEO[3*NE + p] = cut;
    GEO[4*NE + p] = cs*vx;
    GEO[5*NE + p] = cs*vy;
    GEO[6*NE + p] = cs*vz;
    GEO[7*NE + p] = r*((float)(TT-1)/RMAXT);
}

// ---------------------------------------------------------------- filter table build
template<int WOUT>
__global__ void __launch_bounds__(512) k_tab(
    const float* __restrict__ R1, const float* __restrict__ R2, float* __restrict__ TAB)
{
    constexpr int NG = WOUT/4;
    __shared__ float lh[8*100];
    const int tid = threadIdx.x;
    const int t0 = blockIdx.x*8;
    for (int idx = tid; idx < 800; idx += 512) {
        int tl = idx/100, k = idx - tl*100;
        float r = (float)(t0+tl)*(RMAXT/(float)(TT-1));
        float q = r*2.5714285714285716f;
        float a = 0.f;
#pragma unroll
        for (int i = 0; i < 10; ++i) {
            float u = q - (float)i;
            a += __expf(-u*u)*EMBS*R1[i*100 + k];
        }
        lh[idx] = siluf(a*RS10);
    }
    __syncthreads();
    for (int idx = tid; idx < 8*NG; idx += 512) {
        int tl = idx/NG, j = idx - tl*NG;
        const float* hr = lh + tl*100;
        float a0=0.f, a1=0.f, a2=0.f, a3=0.f;
        for (int k = 0; k < 100; ++k) {
            float4 w = *(const float4*)(R2 + (size_t)k*WOUT + 4*j);
            float hk = hr[k];
            a0 = fmaf(hk, w.x, a0); a1 = fmaf(hk, w.y, a1);
            a2 = fmaf(hk, w.z, a2); a3 = fmaf(hk, w.w, a3);
        }
        float4 f = {a0*SR2, a1*SR2, a2*SR2, a3*SR2};
        *(float4*)(TAB + ((size_t)(t0+tl)*NG + j)*4) = f;
    }
}

// ---------------------------------------------------------------- node pre-linear
template<int SIN, int SOUT, int V>
__global__ void __launch_bounds__(256) k_pre(
    const float* __restrict__ xs, const float* __restrict__ xv,
    const float* __restrict__ Ws, const float* __restrict__ Wv,
    float* __restrict__ xs1, float* __restrict__ xv1,
    float ss, float sv)
{
    __shared__ float lws[SIN*SOUT];
    __shared__ float lwv[(V > 0) ? 256 : 1];
    for (int i = threadIdx.x; i < SIN*SOUT; i += blockDim.x) lws[i] = Ws[i];
    if constexpr (V > 0)
        for (int i = threadIdx.x; i < 256; i += blockDim.x) lwv[i] = Wv[i];
    __syncthreads();
    int n = blockIdx.x*blockDim.x + threadIdx.x;
    if (n >= NN) return;
    float xr[SIN];
#pragma unroll
    for (int u = 0; u < SIN; ++u) xr[u] = xs[n*48 + u];
#pragma unroll
    for (int j = 0; j < SOUT; ++j) {
        float a = 0.f;
#pragma unroll
        for (int u = 0; u < SIN; ++u) a += xr[u]*lws[u*SOUT + j];
        xs1[n*SOUT + j] = a*ss;
    }
    if constexpr (V > 0) {
        float vr[48];
#pragma unroll
        for (int i = 0; i < 48; ++i) vr[i] = xv[n*48 + i];
#pragma unroll
        for (int w = 0; w < 16; ++w) {
            float a0 = 0.f, a1 = 0.f, a2 = 0.f;
#pragma unroll
            for (int v = 0; v < 16; ++v) {
                float wt = lwv[v*16 + w];
                a0 += vr[v*3+0]*wt; a1 += vr[v*3+1]*wt; a2 += vr[v*3+2]*wt;
            }
            xv1[n*48 + w*3 + 0] = a0*sv;
            xv1[n*48 + w*3 + 1] = a1*sv;
            xv1[n*48 + w*3 + 2] = a2*sv;
        }
    }
}

// ---------------------------------------------------------------- edge kernel v13 (r16 + unroll 4)
#define LERP(g) \
    const float4 w0 = *(const float4*)(te + (g)*4); \
    const float4 w1 = *(const float4*)(te + (NG + (g))*4); \
    const float a0 = fmaf(fr, w1.x - w0.x, w0.x); \
    const float a1 = fmaf(fr, w1.y - w0.y, w0.y); \
    const float a2 = fmaf(fr, w1.z - w0.z, w0.z); \
    const float a3 = fmaf(fr, w1.w - w0.w, w0.w);

template<int S,int V,int WOUT,bool VEC_OUT,bool FOLD,int WM,int WMS>
__global__ void __launch_bounds__(256) k_edge13(
    const int* __restrict__ SRCg, const float* __restrict__ GEO,
    const float* __restrict__ xs1, const float* __restrict__ xv1,
    const float* __restrict__ TAB, const float* __restrict__ WF,
    float* __restrict__ msg, int p0, int p1, const int* __restrict__ startN)
{
    constexpr int NG = WOUT/4;
    constexpr int NF = FOLD ? (S+V)*8 : (VEC_OUT ? (S+V)*16 : 1);
    const int K = startN[NN];
    const int pb = p0 + blockIdx.x*256;
    if (pb >= K) return;                        // uniform block exit
    __shared__ float lWF[NF];
    if constexpr (NF > 1)
        for (int i = threadIdx.x; i < NF; i += 256) lWF[i] = WF[i];

    const int pe = (p1 < K) ? p1 : K;
    const int p = pb + threadIdx.x;
    const bool valid = (p < pe);
    const int pc = valid ? p : (pe - 1);
    const int src = SRCg[pc];

    const float es0 = GEO[0*NE + pc], es1 = GEO[1*NE + pc];
    const float es2 = GEO[2*NE + pc], es3 = GEO[3*NE + pc];
    const float ev0 = GEO[4*NE + pc], ev1 = GEO[5*NE + pc];
    const float ev2 = GEO[6*NE + pc], tf  = GEO[7*NE + pc];

    int i0 = (int)tf;
    if (i0 > TT-2) i0 = TT-2;
    const float fr = tf - (float)i0;
    const float* te = TAB + (size_t)i0*(NG*4);
    float* msgrow = msg + (size_t)(pc - p0)*WM;

    if constexpr (NF > 1) __syncthreads();

    float fold8[8];
    if constexpr (FOLD) {
#pragma unroll
        for (int j = 0; j < 8; ++j) fold8[j] = 0.f;
    }

    // xsr preload (dies after phase 2)
    float xsr[S];
#pragma unroll
    for (int i = 0; i < S; i += 4) {
        float4 f = *(const float4*)(xs1 + (size_t)src*S + i);
        xsr[i] = f.x; xsr[i+1] = f.y; xsr[i+2] = f.z; xsr[i+3] = f.w;
    }

    // ---- phase 1: w1 scalar messages (groups 0..S-1)
#pragma unroll 4
    for (int gg = 0; gg < S/4; ++gg) {
        float vv[4];
#pragma unroll
        for (int q = 0; q < 4; ++q) {
            const int g = gg*4 + q;
            LERP(g)
            float dv = a0*es0 + a1*es1 + a2*es2 + a3*es3;
            vv[q] = 0.5f*xsr[g]*dv;
            if constexpr (FOLD) {
#pragma unroll
                for (int jj = 0; jj < 8; ++jj)
                    fold8[jj] = fmaf(vv[q], lWF[g*8 + jj], fold8[jj]);
            }
        }
        if constexpr (!FOLD) {
            if (valid) {
                float4 f = {vv[0], vv[1], vv[2], vv[3]};
                *(float4*)(msgrow + gg*4) = f;
            }
        }
    }

    // ---- phase 2: w2 s->v -> tw, then mv = tw (x) ev
    float mv0[VEC_OUT ? 16 : 1], mv1[VEC_OUT ? 16 : 1], mv2[VEC_OUT ? 16 : 1];
    if constexpr (VEC_OUT) {
        float tw[16];
#pragma unroll
        for (int w = 0; w < 16; ++w) tw[w] = 0.f;
#pragma unroll 4
        for (int k = 0; k < S/4; ++k) {
            const int g = S + k;
            LERP(g)
            const int u0 = 4*k;
            float m0 = xsr[u0+0]*a0, m1 = xsr[u0+1]*a1, m2 = xsr[u0+2]*a2, m3 = xsr[u0+3]*a3;
#pragma unroll
            for (int wq = 0; wq < 4; ++wq) {
                float4 f0 = *(const float4*)&lWF[(u0+0)*16 + 4*wq];
                float4 f1 = *(const float4*)&lWF[(u0+1)*16 + 4*wq];
                float4 f2 = *(const float4*)&lWF[(u0+2)*16 + 4*wq];
                float4 f3 = *(const float4*)&lWF[(u0+3)*16 + 4*wq];
                tw[4*wq+0] += m0*f0.x + m1*f1.x + m2*f2.x + m3*f3.x;
                tw[4*wq+1] += m0*f0.y + m1*f1.y + m2*f2.y + m3*f3.y;
                tw[4*wq+2] += m0*f0.z + m1*f1.z + m2*f2.z + m3*f3.z;
                tw[4*wq+3] += m0*f0.w + m1*f1.w + m2*f2.w + m3*f3.w;
            }
        }
#pragma unroll
        for (int w = 0; w < 16; ++w) {
            mv0[w] = tw[w]*ev0; mv1[w] = tw[w]*ev1; mv2[w] = tw[w]*ev2;
        }
    }

    // ---- xvr load, pinned after phase 2 (xsr now dead)
    float xvr[(V > 0) ? 48 : 4];
    if constexpr (V > 0) {
        __builtin_amdgcn_sched_barrier(0);
#pragma unroll
        for (int i = 0; i < 48; i += 4) {
            float4 f = *(const float4*)(xv1 + (size_t)src*48 + i);
            xvr[i] = f.x; xvr[i+1] = f.y; xvr[i+2] = f.z; xvr[i+3] = f.w;
        }
    }

    // ---- phase 3: w3 v->v
    if constexpr (VEC_OUT && V > 0) {
#pragma unroll 4
        for (int u2 = 0; u2 < V; ++u2) {
            const int g = S + S/4 + u2;
            LERP(g)
            float dv = 0.5f*(a0*es0 + a1*es1 + a2*es2 + a3*es3);
            float q0 = dv*xvr[u2*3+0], q1 = dv*xvr[u2*3+1], q2 = dv*xvr[u2*3+2];
#pragma unroll
            for (int wq = 0; wq < 4; ++wq) {
                float4 wf = *(const float4*)&lWF[(S+u2)*16 + 4*wq];
                mv0[4*wq+0] += q0*wf.x; mv0[4*wq+1] += q0*wf.y; mv0[4*wq+2] += q0*wf.z; mv0[4*wq+3] += q0*wf.w;
                mv1[4*wq+0] += q1*wf.x; mv1[4*wq+1] += q1*wf.y; mv1[4*wq+2] += q1*wf.z; mv1[4*wq+3] += q1*wf.w;
                mv2[4*wq+0] += q2*wf.x; mv2[4*wq+1] += q2*wf.y; mv2[4*wq+2] += q2*wf.z; mv2[4*wq+3] += q2*wf.w;
            }
        }
    }

    // ---- phase 4: w4 v->s
    if constexpr (V > 0) {
        constexpr int P4 = VEC_OUT ? (S + S/4 + V) : S;
#pragma unroll
        for (int k = 0; k < V/4; ++k) {
            const int g = P4 + k;
            LERP(g)
            const int u0 = 4*k;
            float d0 = xvr[(u0+0)*3]*ev0 + xvr[(u0+0)*3+1]*ev1 + xvr[(u0+0)*3+2]*ev2;
            float d1 = xvr[(u0+1)*3]*ev0 + xvr[(u0+1)*3+1]*ev1 + xvr[(u0+1)*3+2]*ev2;
            float d2 = xvr[(u0+2)*3]*ev0 + xvr[(u0+2)*3+1]*ev1 + xvr[(u0+2)*3+2]*ev2;
            float d3 = xvr[(u0+3)*3]*ev0 + xvr[(u0+3)*3+1]*ev1 + xvr[(u0+3)*3+2]*ev2;
            float v0 = a0*d0*ISQ3, v1 = a1*d1*ISQ3, v2 = a2*d2*ISQ3, v3 = a3*d3*ISQ3;
            if constexpr (FOLD) {
#pragma unroll
                for (int jj = 0; jj < 8; jj += 4) {
                    float4 f0 = *(const float4*)&lWF[(S+u0+0)*8 + jj];
                    float4 f1 = *(const float4*)&lWF[(S+u0+1)*8 + jj];
                    float4 f2 = *(const float4*)&lWF[(S+u0+2)*8 + jj];
                    float4 f3 = *(const float4*)&lWF[(S+u0+3)*8 + jj];
                    fold8[jj+0] += v0*f0.x + v1*f1.x + v2*f2.x + v3*f3.x;
                    fold8[jj+1] += v0*f0.y + v1*f1.y + v2*f2.y + v3*f3.y;
                    fold8[jj+2] += v0*f0.z + v1*f1.z + v2*f2.z + v3*f3.z;
                    fold8[jj+3] += v0*f0.w + v1*f1.w + v2*f2.w + v3*f3.w;
                }
            } else {
                if (valid) {
                    float4 f = {v0, v1, v2, v3};
                    *(float4*)(msgrow + S + u0) = f;
                }
            }
        }
    }

    if constexpr (FOLD) {
        if (valid) {
            float4 f0 = {fold8[0], fold8[1], fold8[2], fold8[3]};
            float4 f1 = {fold8[4], fold8[5], fold8[6], fold8[7]};
            *(float4*)(msgrow + 0) = f0;
            *(float4*)(msgrow + 4) = f1;
        }
    } else if constexpr (VEC_OUT) {
        if (valid) {
#pragma unroll
            for (int w = 0; w < 16; w += 4) {
                float4 f0 = {mv0[w], mv0[w+1], mv0[w+2], mv0[w+3]};
                float4 f1 = {mv1[w], mv1[w+1], mv1[w+2], mv1[w+3]};
                float4 f2 = {mv2[w], mv2[w+1], mv2[w+2], mv2[w+3]};
                *(float4*)(msgrow + WMS + 0*16 + w) = f0;
                *(float4*)(msgrow + WMS + 1*16 + w) = f1;
                *(float4*)(msgrow + WMS + 2*16 + w) = f2;
            }
        }
    }
}

// ---------------------------------------------------------------- segmented sum (row-major msg, float4)
template<int W>
__global__ void __launch_bounds__(256) k_segsum(
    const float* __restrict__ msg, float* __restrict__ Y,
    const int* __restrict__ start, int p0, int p1, int first)
{
    constexpr int W4 = W/4;
    int idx = blockIdx.x*blockDim.x + threadIdx.x;
    if (idx >= NN*W4) return;
    int n = idx / W4;
    int c4 = idx - n*W4;
    int lo = start[n], hi = start[n+1];
    if (lo < p0) lo = p0;
    if (hi > p1) hi = p1;
    float4 s = {0.f, 0.f, 0.f, 0.f};
    if (lo < hi) {
        const float* q = msg + (size_t)(lo - p0)*W + c4*4;
        for (int p = lo; p < hi; ++p) {
            float4 v = *(const float4*)q;
            s.x += v.x; s.y += v.y; s.z += v.z; s.w += v.w;
            q += W;
        }
    }
    float* yp = Y + (size_t)n*W + c4*4;
    if (first) *(float4*)yp = s;
    else if (lo < hi) {
        float4 y = *(const float4*)yp;
        y.x += s.x; y.y += s.y; y.z += s.z; y.w += s.w;
        *(float4*)yp = y;
    }
}

// ---------------------------------------------------------------- node post + gate (in-place; Y row-major)
template<int SIN, int YSW, int WST, bool HASV>
__global__ void __launch_bounds__(256) k_post(
    float* __restrict__ xsv, float* __restrict__ xvv,
    const float* __restrict__ Y,
    const float* __restrict__ scs, const float* __restrict__ scv,
    const float* __restrict__ l2s,
    float s_sc, float s_l2s, float s_scv, float s_l2v)
{
    __shared__ float Lscs[SIN*48];
    __shared__ float Ll2s[YSW*48];
    __shared__ float Lscv[HASV ? 256 : 1];
    for (int i = threadIdx.x; i < SIN*48; i += blockDim.x) Lscs[i] = scs[i];
    for (int i = threadIdx.x; i < YSW*48; i += blockDim.x) Ll2s[i] = l2s[i];
    if constexpr (HASV)
        for (int i = threadIdx.x; i < 256; i += blockDim.x) Lscv[i] = scv[i];
    __syncthreads();
    int n = blockIdx.x*blockDim.x + threadIdx.x;
    if (n >= NN) return;
    const float* yrow = Y + (size_t)n*WST;
    float xr[SIN];
#pragma unroll
    for (int u = 0; u < SIN; ++u) xr[u] = xsv[n*48 + u];
    float yr[YSW];
#pragma unroll
    for (int t = 0; t < YSW; ++t) yr[t] = yrow[t]*ISNN;
    float os[48];
    const float A = C_S*s_sc, B = C_X*s_l2s;
#pragma unroll
    for (int j = 0; j < 48; ++j) {
        float a = 0.f, b = 0.f;
#pragma unroll
        for (int u = 0; u < SIN; ++u) a += xr[u]*Lscs[u*48 + j];
#pragma unroll
        for (int t = 0; t < YSW; ++t) b += yr[t]*Ll2s[t*48 + j];
        os[j] = A*a + B*b;
    }
#pragma unroll
    for (int u = 0; u < 32; ++u) xsv[n*48 + u] = siluf(os[u]);
    float gg[16];
#pragma unroll
    for (int t = 0; t < 16; ++t) gg[t] = sigmf(os[32 + t]);
    const float sc3 = ISNN*s_l2v*(HASV ? C_X : 1.0f);
    if constexpr (HASV) {
        float vr[48];
#pragma unroll
        for (int i = 0; i < 48; ++i) vr[i] = xvv[n*48 + i];
        const float Av = C_S*s_scv;
#pragma unroll
        for (int w = 0; w < 16; ++w) {
            float s0 = 0.f, s1 = 0.f, s2 = 0.f;
#pragma unroll
            for (int v = 0; v < 16; ++v) {
                float wt = Lscv[v*16 + w];
                s0 += vr[v*3+0]*wt; s1 += vr[v*3+1]*wt; s2 += vr[v*3+2]*wt;
            }
            xvv[n*48 + w*3 + 0] = (Av*s0 + sc3*yrow[YSW + 0*16 + w])*gg[w];
            xvv[n*48 + w*3 + 1] = (Av*s1 + sc3*yrow[YSW + 1*16 + w])*gg[w];
            xvv[n*48 + w*3 + 2] = (Av*s2 + sc3*yrow[YSW + 2*16 + w])*gg[w];
        }
    } else {
#pragma unroll
        for (int w = 0; w < 16; ++w) {
            xvv[n*48 + w*3 + 0] = sc3*yrow[YSW + 0*16 + w]*gg[w];
            xvv[n*48 + w*3 + 1] = sc3*yrow[YSW + 1*16 + w]*gg[w];
            xvv[n*48 + w*3 + 2] = sc3*yrow[YSW + 2*16 + w]*gg[w];
        }
    }
}

// ---------------------------------------------------------------- layer4 post + head
__global__ void __launch_bounds__(256) k_final(
    const float* __restrict__ xsv, const float* __restrict__ Y8,
    const float* __restrict__ scs,
    const float* __restrict__ Wh, const float* __restrict__ bh,
    float* __restrict__ out)
{
    __shared__ float Lscs[32*8];
    __shared__ float Lwh[24];
    __shared__ float Lbh[3];
    for (int i = threadIdx.x; i < 32*8; i += blockDim.x) Lscs[i] = scs[i];
    if (threadIdx.x < 24) Lwh[threadIdx.x] = Wh[threadIdx.x];
    if (threadIdx.x < 3)  Lbh[threadIdx.x] = bh[threadIdx.x];
    __syncthreads();
    int n = blockIdx.x*blockDim.x + threadIdx.x;
    if (n >= NN) return;
    float xr[32];
#pragma unroll
    for (int u = 0; u < 32; ++u) xr[u] = xsv[n*48 + u];
    const float CB = C_X*RS48*ISNN;
    float s8[8];
#pragma unroll
    for (int j = 0; j < 8; ++j) {
        float a = 0.f;
#pragma unroll
        for (int u = 0; u < 32; ++u) a += xr[u]*Lscs[u*8 + j];
        s8[j] = C_S*RS32*a + CB*Y8[n*8 + j];
    }
#pragma unroll
    for (int c = 0; c < 3; ++c) {
        float o = Lbh[c];
#pragma unroll
        for (int j = 0; j < 8; ++j) o += s8[j]*Lwh[j*3 + c];
        out[n*3 + c] = o;
    }
}

// ---------------------------------------------------------------- launcher
extern "C" void kernel_launch(void* const* d_in, const int* in_sizes, int n_in,
                              void* d_out, int out_size, void* d_ws, size_t ws_size,
                              hipStream_t stream)
{
    const float* pos       = (const float*)d_in[0];
    const float* onehot    = (const float*)d_in[1];
    const float* eattr     = (const float*)d_in[2];
    const float* W_embed   = (const float*)d_in[3];
    const float* b_embed   = (const float*)d_in[4];
    const float* l1_lin1_s = (const float*)d_in[5];
    const float* l1_sc_s   = (const float*)d_in[6];
    const float* l1_R1     = (const float*)d_in[7];
    const float* l1_R2     = (const float*)d_in[8];
    const float* l1_lin2_s = (const float*)d_in[9];
    const float* l1_lin2_v = (const float*)d_in[10];
    const float* l2_lin1_s = (const float*)d_in[11];
    const float* l2_lin1_v = (const float*)d_in[12];
    const float* l2_sc_s   = (const float*)d_in[13];
    const float* l2_sc_v   = (const float*)d_in[14];
    const float* l2_R1     = (const float*)d_in[15];
    const float* l2_R2     = (const float*)d_in[16];
    const float* l2_lin2_s = (const float*)d_in[17];
    const float* l2_lin2_v = (const float*)d_in[18];
    const float* l3_lin1_s = (const float*)d_in[19];
    const float* l3_lin1_v = (const float*)d_in[20];
    const float* l3_sc_s   = (const float*)d_in[21];
    const float* l3_sc_v   = (const float*)d_in[22];
    const float* l3_R1     = (const float*)d_in[23];
    const float* l3_R2     = (const float*)d_in[24];
    const float* l3_lin2_s = (const float*)d_in[25];
    const float* l3_lin2_v = (const float*)d_in[26];
    const float* l4_lin1_s = (const float*)d_in[27];
    const float* l4_lin1_v = (const float*)d_in[28];
    const float* l4_sc_s   = (const float*)d_in[29];
    const float* l4_R1     = (const float*)d_in[30];
    const float* l4_R2     = (const float*)d_in[31];
    const float* l4_lin2_s = (const float*)d_in[32];
    const float* W_head    = (const float*)d_in[33];
    const float* b_head    = (const float*)d_in[34];
    const int*   eidx      = (const int*)d_in[35];
    const int* srcv = eidx;
    const int* dstv = eidx + NE;

    float* ws = (float*)d_ws;
    size_t off = 0;
    float* XS     = ws + off; off += 48ull*NN;
    float* XV     = ws + off; off += 48ull*NN;
    float* XS1    = ws + off; off += 32ull*NN;
    float* XV1    = ws + off; off += 48ull*NN;
    float* Y      = ws + off; off += 96ull*NN;
    float* TAB    = ws + off; off += (size_t)TT*60*4;
    int*   start  = (int*)(ws + off); off += ((NN + 1 + 3) & ~3);
    int*   cursor = (int*)(ws + off); off += NN;
    int*   perm   = (int*)(ws + off); off += NE;
    int*   SRCg   = (int*)(ws + off); off += NE;
    int*   LIVEf  = (int*)(ws + off); off += NE;
    float* GEO    = ws + off; off += 8ull*NE;
    float* MSG    = ws + off;
    size_t totalFloats = ws_size/4;
    size_t msgCap = (totalFloats > off) ? (totalFloats - off) : 0;

    dim3 th(256), be((NE + 255)/256), bn((NN + 255)/256);

    long ECall;
    {
        long cap = (long)(msgCap/96) & ~255L;
        ECall = (cap >= NE) ? NE : cap;     // single chunk if workspace allows
        if (ECall < 4096) ECall = 4096;
    }

    // ---- live classify + dst sort + geometry pre-gather
    hipMemsetAsync(cursor, 0, NN*sizeof(int), stream);
    k_hist2<<<be, th, 0, stream>>>(pos, srcv, dstv, cursor, LIVEf);
    k_scan<<<1, 1024, 0, stream>>>(cursor, start);
    k_scatter2<<<be, th, 0, stream>>>(dstv, LIVEf, cursor, perm);
    k_geo<<<be, th, 0, stream>>>(pos, eattr, srcv, dstv, perm, start, SRCg, GEO);

    k_embed<<<(NN*64 + 255)/256, th, 0, stream>>>(onehot, W_embed, b_embed, XS);

    dim3 tb(512), gb(TT/8);

    // ---- layer 1 (S=16, V=0, WOUT=80; msg width 64)
    {
        k_pre<16,16,0><<<bn, th, 0, stream>>>(XS, nullptr, l1_lin1_s, nullptr, XS1, XV1, RS16, RS16);
        k_tab<80><<<gb, tb, 0, stream>>>(l1_R1, l1_R2, TAB);
        for (long c0 = 0; c0 < NE; c0 += ECall) {
            int p0 = (int)c0, p1 = (int)((c0 + ECall < NE) ? c0 + ECall : NE);
            dim3 ge(((p1-p0) + 255)/256);
            k_edge13<16,0,80,true,false,64,16><<<ge, th, 0, stream>>>(
                SRCg, GEO, XS1, XV1, TAB, l1_lin2_v, MSG, p0, p1, start);
            dim3 gs((NN*16 + 255)/256);
            k_segsum<64><<<gs, th, 0, stream>>>(MSG, Y, start, p0, p1, c0 == 0);
        }
        k_post<16,16,64,false><<<bn, th, 0, stream>>>(XS, XV, Y, l1_sc_s, nullptr, l1_lin2_s,
                                                      RS16, RS16, 0.f, RS16);
    }

    // ---- layers 2,3 (S=32, V=16, WOUT=240; msg width 96)
    const float* L2w[2][6] = {
        {l2_lin1_s, l2_lin1_v, l2_R1, l2_R2, l2_lin2_v, l2_lin2_s},
        {l3_lin1_s, l3_lin1_v, l3_R1, l3_R2, l3_lin2_v, l3_lin2_s}};
    const float* L2sc[2][2] = {{l2_sc_s, l2_sc_v}, {l3_sc_s, l3_sc_v}};
    for (int L = 0; L < 2; ++L) {
        k_pre<32,32,16><<<bn, th, 0, stream>>>(XS, XV, L2w[L][0], L2w[L][1], XS1, XV1, RS32, RS16);
        k_tab<240><<<gb, tb, 0, stream>>>(L2w[L][2], L2w[L][3], TAB);
        for (long c0 = 0; c0 < NE; c0 += ECall) {
            int p0 = (int)c0, p1 = (int)((c0 + ECall < NE) ? c0 + ECall : NE);
            dim3 ge(((p1-p0) + 255)/256);
            k_edge13<32,16,240,true,false,96,48><<<ge, th, 0, stream>>>(
                SRCg, GEO, XS1, XV1, TAB, L2w[L][4], MSG, p0, p1, start);
            dim3 gs((NN*24 + 255)/256);
            k_segsum<96><<<gs, th, 0, stream>>>(MSG, Y, start, p0, p1, c0 == 0);
        }
        k_post<32,48,96,true><<<bn, th, 0, stream>>>(XS, XV, Y, L2sc[L][0], L2sc[L][1], L2w[L][5],
                                                     RS32, RS48, RS16, RS48);
    }

    // ---- layer 4 (S=32, V=16, WOUT=144; lin2_s folded -> msg width 8)
    {
        k_pre<32,32,16><<<bn, th, 0, stream>>>(XS, XV, l4_lin1_s, l4_lin1_v, XS1, XV1, RS32, RS16);
        k_tab<144><<<gb, tb, 0, stream>>>(l4_R1, l4_R2, TAB);
        for (long c0 = 0; c0 < NE; c0 += ECall) {
            int p0 = (int)c0, p1 = (int)((c0 + ECall < NE) ? c0 + ECall : NE);
            dim3 ge(((p1-p0) + 255)/256);
            k_edge13<32,16,144,false,true,8,48><<<ge, th, 0, stream>>>(
                SRCg, GEO, XS1, XV1, TAB, l4_lin2_s, MSG, p0, p1, start);
            dim3 gs((NN*2 + 255)/256);
            k_segsum<8><<<gs, th, 0, stream>>>(MSG, Y, start, p0, p1, c0 == 0);
        }
        k_final<<<bn, th, 0, stream>>>(XS, Y, l4_sc_s, W_head, b_head, (float*)d_out);
    }
}

// Round 18
// 1584.479 us; speedup vs baseline: 1.0227x; 1.0227x over previous
//
#include <hip/hip_runtime.h>

#define NN 50000
#define NE 800000
#define TT 2048
#define RMAXT 6.0f

__device__ __forceinline__ float siluf(float x){ return x/(1.0f+__expf(-x)); }
__device__ __forceinline__ float sigmf(float x){ return 1.0f/(1.0f+__expf(-x)); }

#define C_S 0.3826834323650898f
#define C_X 0.9238795325112867f
#define RS16 0.25f
#define RS32 0.1767766952966369f
#define RS48 0.14433756729740643f
#define RS10 0.31622776601683794f
#define SR2  0.1f
#define ISQ3 0.5773502691896258f
#define SQ3F 1.7320508075688772f
#define ISNN 0.25f
#define EMBS 2.8234621965789103f
#define PIF  3.14159265358979323846f

// LESSON (r3/5/7/8): every kernel gets __launch_bounds__(block_size).
// LESSON (r12/r15): scatter-atomic / per-thread-column LDS reduces lose;
// row-major MSG + float4 segsum sweep is the proven reduction.
// LESSON (r14): fused MLP+reduce node blocks serialize edges.
// LESSON (r16): unroll 2/2/4 -> VGPR 88, occupancy 2x, -17% edge time.
// LESSON (r17): TT=2048 (TAB L2-resident) cuts edge FETCH/time; unroll 4 no gain.
// r18 = r16 unroll schedule + TT=2048 (final).

// ---------------------------------------------------------------- embed (wave per node)
__global__ void __launch_bounds__(256) k_embed(
    const float* __restrict__ oh, const float* __restrict__ W,
    const float* __restrict__ b, float* __restrict__ xs)
{
    __shared__ float lw[118*16];
    __shared__ float lb[16];
    for (int i = threadIdx.x; i < 118*16; i += blockDim.x) lw[i] = W[i];
    if (threadIdx.x < 16) lb[threadIdx.x] = b[threadIdx.x];
    __syncthreads();
    int gw = (blockIdx.x*blockDim.x + threadIdx.x) >> 6;
    int lane = threadIdx.x & 63;
    if (gw >= NN) return;
    float acc[16];
#pragma unroll
    for (int j = 0; j < 16; ++j) acc[j] = 0.f;
    for (int i = lane; i < 118; i += 64) {
        float o = oh[(size_t)gw*118 + i];
#pragma unroll
        for (int j = 0; j < 16; ++j) acc[j] += o*lw[i*16 + j];
    }
#pragma unroll
    for (int d = 32; d; d >>= 1) {
#pragma unroll
        for (int j = 0; j < 16; ++j) acc[j] += __shfl_xor(acc[j], d, 64);
    }
    if (lane == 0) {
        float* o = xs + (size_t)gw*48;
#pragma unroll
        for (int j = 0; j < 16; ++j) o[j] = acc[j] + lb[j];
    }
}

// ---------------------------------------------------------------- live classify + dst hist
__global__ void __launch_bounds__(256) k_hist2(
    const float* __restrict__ pos, const int* __restrict__ srcv,
    const int* __restrict__ dstv, int* __restrict__ cnt, int* __restrict__ livef)
{
    int e = blockIdx.x*blockDim.x + threadIdx.x;
    if (e >= NE) return;
    int s = srcv[e], d = dstv[e];
    float vx = pos[3*s+0]-pos[3*d+0], vy = pos[3*s+1]-pos[3*d+1], vz = pos[3*s+2]-pos[3*d+2];
    float r = sqrtf(vx*vx+vy*vy+vz*vz + 1e-12f);
    float tf = r*((float)(TT-1)/RMAXT);
    int lv = (tf < (float)(TT-1)) ? 1 : 0;   // r >= 6 -> filter == 0 -> edge dead
    livef[e] = lv;
    if (lv) atomicAdd(&cnt[d], 1);
}

// exclusive scan: cnt (live counts) -> start[NN+1]; cnt re-initialized to start
__global__ void __launch_bounds__(1024) k_scan(
    int* __restrict__ cnt, int* __restrict__ start)
{
    __shared__ int part[1024];
    const int L = (NN + 1023)/1024;
    int t = threadIdx.x;
    int b0 = t*L, b1 = b0 + L; if (b1 > NN) b1 = NN; if (b0 > NN) b0 = NN;
    int s = 0;
    for (int i = b0; i < b1; ++i) s += cnt[i];
    part[t] = s;
    __syncthreads();
    for (int off = 1; off < 1024; off <<= 1) {
        int vv = (t >= off) ? part[t-off] : 0;
        __syncthreads();
        part[t] += vv;
        __syncthreads();
    }
    int run = (t == 0) ? 0 : part[t-1];
    for (int i = b0; i < b1; ++i) {
        int cc = cnt[i];
        start[i] = run;
        cnt[i] = run;
        run += cc;
    }
    if (t == 1023) start[NN] = part[1023];
}

__global__ void __launch_bounds__(256) k_scatter2(
    const int* __restrict__ dstv, const int* __restrict__ livef,
    int* __restrict__ cursor, int* __restrict__ perm)
{
    int e = blockIdx.x*blockDim.x + threadIdx.x;
    if (e < NE && livef[e]) {
        int p = atomicAdd(&cursor[dstv[e]], 1);
        perm[p] = e;
    }
}

// ---------------------------------------------------------------- geometry pre-gather (live, dst-sorted, column-major)
__global__ void __launch_bounds__(256) k_geo(
    const float* __restrict__ pos, const float* __restrict__ ea,
    const int* __restrict__ srcv, const int* __restrict__ dstv,
    const int* __restrict__ perm, const int* __restrict__ startN,
    int* __restrict__ SRCg, float* __restrict__ GEO)
{
    int p = blockIdx.x*blockDim.x + threadIdx.x;
    if (p >= startN[NN]) return;
    int e = perm[p];
    int s = srcv[e], d = dstv[e];
    float vx = pos[3*s+0] - pos[3*d+0];
    float vy = pos[3*s+1] - pos[3*d+1];
    float vz = pos[3*s+2] - pos[3*d+2];
    float r  = sqrtf(vx*vx + vy*vy + vz*vz + 1e-12f);
    float ir = 1.0f/r;
    float uu = 2.0f*(r*(1.0f/3.5f) - 1.0f);
    float cut = (uu > 0.0f) ? 0.0f
              : ((uu < -1.0f) ? 1.0f : 0.5f*(1.0f - cosf(PIF*uu)));
    float cs = cut*SQ3F*ir;
    SRCg[p] = s;
    GEO[0*NE + p] = ea[3*e+0];
    GEO[1*NE + p] = ea[3*e+1];
    GEO[2*NE + p] = ea[3*e+2];
    GEO[3*NE + p] = cut;
    GEO[4*NE + p] = cs*vx;
    GEO[5*NE + p] = cs*vy;
    GEO[6*NE + p] = cs*vz;
    GEO[7*NE + p] = r*((float)(TT-1)/RMAXT);
}

// ---------------------------------------------------------------- filter table build
template<int WOUT>
__global__ void __launch_bounds__(512) k_tab(
    const float* __restrict__ R1, const float* __restrict__ R2, float* __restrict__ TAB)
{
    constexpr int NG = WOUT/4;
    __shared__ float lh[8*100];
    const int tid = threadIdx.x;
    const int t0 = blockIdx.x*8;
    for (int idx = tid; idx < 800; idx += 512) {
        int tl = idx/100, k = idx - tl*100;
        float r = (float)(t0+tl)*(RMAXT/(float)(TT-1));
        float q = r*2.5714285714285716f;
        float a = 0.f;
#pragma unroll
        for (int i = 0; i < 10; ++i) {
            float u = q - (float)i;
            a += __expf(-u*u)*EMBS*R1[i*100 + k];
        }
        lh[idx] = siluf(a*RS10);
    }
    __syncthreads();
    for (int idx = tid; idx < 8*NG; idx += 512) {
        int tl = idx/NG, j = idx - tl*NG;
        const float* hr = lh + tl*100;
        float a0=0.f, a1=0.f, a2=0.f, a3=0.f;
        for (int k = 0; k < 100; ++k) {
            float4 w = *(const float4*)(R2 + (size_t)k*WOUT + 4*j);
            float hk = hr[k];
            a0 = fmaf(hk, w.x, a0); a1 = fmaf(hk, w.y, a1);
            a2 = fmaf(hk, w.z, a2); a3 = fmaf(hk, w.w, a3);
        }
        float4 f = {a0*SR2, a1*SR2, a2*SR2, a3*SR2};
        *(float4*)(TAB + ((size_t)(t0+tl)*NG + j)*4) = f;
    }
}

// ---------------------------------------------------------------- node pre-linear
template<int SIN, int SOUT, int V>
__global__ void __launch_bounds__(256) k_pre(
    const float* __restrict__ xs, const float* __restrict__ xv,
    const float* __restrict__ Ws, const float* __restrict__ Wv,
    float* __restrict__ xs1, float* __restrict__ xv1,
    float ss, float sv)
{
    __shared__ float lws[SIN*SOUT];
    __shared__ float lwv[(V > 0) ? 256 : 1];
    for (int i = threadIdx.x; i < SIN*SOUT; i += blockDim.x) lws[i] = Ws[i];
    if constexpr (V > 0)
        for (int i = threadIdx.x; i < 256; i += blockDim.x) lwv[i] = Wv[i];
    __syncthreads();
    int n = blockIdx.x*blockDim.x + threadIdx.x;
    if (n >= NN) return;
    float xr[SIN];
#pragma unroll
    for (int u = 0; u < SIN; ++u) xr[u] = xs[n*48 + u];
#pragma unroll
    for (int j = 0; j < SOUT; ++j) {
        float a = 0.f;
#pragma unroll
        for (int u = 0; u < SIN; ++u) a += xr[u]*lws[u*SOUT + j];
        xs1[n*SOUT + j] = a*ss;
    }
    if constexpr (V > 0) {
        float vr[48];
#pragma unroll
        for (int i = 0; i < 48; ++i) vr[i] = xv[n*48 + i];
#pragma unroll
        for (int w = 0; w < 16; ++w) {
            float a0 = 0.f, a1 = 0.f, a2 = 0.f;
#pragma unroll
            for (int v = 0; v < 16; ++v) {
                float wt = lwv[v*16 + w];
                a0 += vr[v*3+0]*wt; a1 += vr[v*3+1]*wt; a2 += vr[v*3+2]*wt;
            }
            xv1[n*48 + w*3 + 0] = a0*sv;
            xv1[n*48 + w*3 + 1] = a1*sv;
            xv1[n*48 + w*3 + 2] = a2*sv;
        }
    }
}

// ---------------------------------------------------------------- edge kernel v13 (r16 unrolls, TT=2048)
#define LERP(g) \
    const float4 w0 = *(const float4*)(te + (g)*4); \
    const float4 w1 = *(const float4*)(te + (NG + (g))*4); \
    const float a0 = fmaf(fr, w1.x - w0.x, w0.x); \
    const float a1 = fmaf(fr, w1.y - w0.y, w0.y); \
    const float a2 = fmaf(fr, w1.z - w0.z, w0.z); \
    const float a3 = fmaf(fr, w1.w - w0.w, w0.w);

template<int S,int V,int WOUT,bool VEC_OUT,bool FOLD,int WM,int WMS>
__global__ void __launch_bounds__(256) k_edge13(
    const int* __restrict__ SRCg, const float* __restrict__ GEO,
    const float* __restrict__ xs1, const float* __restrict__ xv1,
    const float* __restrict__ TAB, const float* __restrict__ WF,
    float* __restrict__ msg, int p0, int p1, const int* __restrict__ startN)
{
    constexpr int NG = WOUT/4;
    constexpr int NF = FOLD ? (S+V)*8 : (VEC_OUT ? (S+V)*16 : 1);
    const int K = startN[NN];
    const int pb = p0 + blockIdx.x*256;
    if (pb >= K) return;                        // uniform block exit
    __shared__ float lWF[NF];
    if constexpr (NF > 1)
        for (int i = threadIdx.x; i < NF; i += 256) lWF[i] = WF[i];

    const int pe = (p1 < K) ? p1 : K;
    const int p = pb + threadIdx.x;
    const bool valid = (p < pe);
    const int pc = valid ? p : (pe - 1);
    const int src = SRCg[pc];

    const float es0 = GEO[0*NE + pc], es1 = GEO[1*NE + pc];
    const float es2 = GEO[2*NE + pc], es3 = GEO[3*NE + pc];
    const float ev0 = GEO[4*NE + pc], ev1 = GEO[5*NE + pc];
    const float ev2 = GEO[6*NE + pc], tf  = GEO[7*NE + pc];

    int i0 = (int)tf;
    if (i0 > TT-2) i0 = TT-2;
    const float fr = tf - (float)i0;
    const float* te = TAB + (size_t)i0*(NG*4);
    float* msgrow = msg + (size_t)(pc - p0)*WM;

    if constexpr (NF > 1) __syncthreads();

    float fold8[8];
    if constexpr (FOLD) {
#pragma unroll
        for (int j = 0; j < 8; ++j) fold8[j] = 0.f;
    }

    // xsr preload (dies after phase 2)
    float xsr[S];
#pragma unroll
    for (int i = 0; i < S; i += 4) {
        float4 f = *(const float4*)(xs1 + (size_t)src*S + i);
        xsr[i] = f.x; xsr[i+1] = f.y; xsr[i+2] = f.z; xsr[i+3] = f.w;
    }

    // ---- phase 1: w1 scalar messages (groups 0..S-1)
#pragma unroll 2
    for (int gg = 0; gg < S/4; ++gg) {
        float vv[4];
#pragma unroll
        for (int q = 0; q < 4; ++q) {
            const int g = gg*4 + q;
            LERP(g)
            float dv = a0*es0 + a1*es1 + a2*es2 + a3*es3;
            vv[q] = 0.5f*xsr[g]*dv;
            if constexpr (FOLD) {
#pragma unroll
                for (int jj = 0; jj < 8; ++jj)
                    fold8[jj] = fmaf(vv[q], lWF[g*8 + jj], fold8[jj]);
            }
        }
        if constexpr (!FOLD) {
            if (valid) {
                float4 f = {vv[0], vv[1], vv[2], vv[3]};
                *(float4*)(msgrow + gg*4) = f;
            }
        }
    }

    // ---- phase 2: w2 s->v -> tw, then mv = tw (x) ev
    float mv0[VEC_OUT ? 16 : 1], mv1[VEC_OUT ? 16 : 1], mv2[VEC_OUT ? 16 : 1];
    if constexpr (VEC_OUT) {
        float tw[16];
#pragma unroll
        for (int w = 0; w < 16; ++w) tw[w] = 0.f;
#pragma unroll 2
        for (int k = 0; k < S/4; ++k) {
            const int g = S + k;
            LERP(g)
            const int u0 = 4*k;
            float m0 = xsr[u0+0]*a0, m1 = xsr[u0+1]*a1, m2 = xsr[u0+2]*a2, m3 = xsr[u0+3]*a3;
#pragma unroll
            for (int wq = 0; wq < 4; ++wq) {
                float4 f0 = *(const float4*)&lWF[(u0+0)*16 + 4*wq];
                float4 f1 = *(const float4*)&lWF[(u0+1)*16 + 4*wq];
                float4 f2 = *(const float4*)&lWF[(u0+2)*16 + 4*wq];
                float4 f3 = *(const float4*)&lWF[(u0+3)*16 + 4*wq];
                tw[4*wq+0] += m0*f0.x + m1*f1.x + m2*f2.x + m3*f3.x;
                tw[4*wq+1] += m0*f0.y + m1*f1.y + m2*f2.y + m3*f3.y;
                tw[4*wq+2] += m0*f0.z + m1*f1.z + m2*f2.z + m3*f3.z;
                tw[4*wq+3] += m0*f0.w + m1*f1.w + m2*f2.w + m3*f3.w;
            }
        }
#pragma unroll
        for (int w = 0; w < 16; ++w) {
            mv0[w] = tw[w]*ev0; mv1[w] = tw[w]*ev1; mv2[w] = tw[w]*ev2;
        }
    }

    // ---- xvr load, pinned after phase 2 (xsr now dead)
    float xvr[(V > 0) ? 48 : 4];
    if constexpr (V > 0) {
        __builtin_amdgcn_sched_barrier(0);
#pragma unroll
        for (int i = 0; i < 48; i += 4) {
            float4 f = *(const float4*)(xv1 + (size_t)src*48 + i);
            xvr[i] = f.x; xvr[i+1] = f.y; xvr[i+2] = f.z; xvr[i+3] = f.w;
        }
    }

    // ---- phase 3: w3 v->v
    if constexpr (VEC_OUT && V > 0) {
#pragma unroll 4
        for (int u2 = 0; u2 < V; ++u2) {
            const int g = S + S/4 + u2;
            LERP(g)
            float dv = 0.5f*(a0*es0 + a1*es1 + a2*es2 + a3*es3);
            float q0 = dv*xvr[u2*3+0], q1 = dv*xvr[u2*3+1], q2 = dv*xvr[u2*3+2];
#pragma unroll
            for (int wq = 0; wq < 4; ++wq) {
                float4 wf = *(const float4*)&lWF[(S+u2)*16 + 4*wq];
                mv0[4*wq+0] += q0*wf.x; mv0[4*wq+1] += q0*wf.y; mv0[4*wq+2] += q0*wf.z; mv0[4*wq+3] += q0*wf.w;
                mv1[4*wq+0] += q1*wf.x; mv1[4*wq+1] += q1*wf.y; mv1[4*wq+2] += q1*wf.z; mv1[4*wq+3] += q1*wf.w;
                mv2[4*wq+0] += q2*wf.x; mv2[4*wq+1] += q2*wf.y; mv2[4*wq+2] += q2*wf.z; mv2[4*wq+3] += q2*wf.w;
            }
        }
    }

    // ---- phase 4: w4 v->s
    if constexpr (V > 0) {
        constexpr int P4 = VEC_OUT ? (S + S/4 + V) : S;
#pragma unroll
        for (int k = 0; k < V/4; ++k) {
            const int g = P4 + k;
            LERP(g)
            const int u0 = 4*k;
            float d0 = xvr[(u0+0)*3]*ev0 + xvr[(u0+0)*3+1]*ev1 + xvr[(u0+0)*3+2]*ev2;
            float d1 = xvr[(u0+1)*3]*ev0 + xvr[(u0+1)*3+1]*ev1 + xvr[(u0+1)*3+2]*ev2;
            float d2 = xvr[(u0+2)*3]*ev0 + xvr[(u0+2)*3+1]*ev1 + xvr[(u0+2)*3+2]*ev2;
            float d3 = xvr[(u0+3)*3]*ev0 + xvr[(u0+3)*3+1]*ev1 + xvr[(u0+3)*3+2]*ev2;
            float v0 = a0*d0*ISQ3, v1 = a1*d1*ISQ3, v2 = a2*d2*ISQ3, v3 = a3*d3*ISQ3;
            if constexpr (FOLD) {
#pragma unroll
                for (int jj = 0; jj < 8; jj += 4) {
                    float4 f0 = *(const float4*)&lWF[(S+u0+0)*8 + jj];
                    float4 f1 = *(const float4*)&lWF[(S+u0+1)*8 + jj];
                    float4 f2 = *(const float4*)&lWF[(S+u0+2)*8 + jj];
                    float4 f3 = *(const float4*)&lWF[(S+u0+3)*8 + jj];
                    fold8[jj+0] += v0*f0.x + v1*f1.x + v2*f2.x + v3*f3.x;
                    fold8[jj+1] += v0*f0.y + v1*f1.y + v2*f2.y + v3*f3.y;
                    fold8[jj+2] += v0*f0.z + v1*f1.z + v2*f2.z + v3*f3.z;
                    fold8[jj+3] += v0*f0.w + v1*f1.w + v2*f2.w + v3*f3.w;
                }
            } else {
                if (valid) {
                    float4 f = {v0, v1, v2, v3};
                    *(float4*)(msgrow + S + u0) = f;
                }
            }
        }
    }

    if constexpr (FOLD) {
        if (valid) {
            float4 f0 = {fold8[0], fold8[1], fold8[2], fold8[3]};
            float4 f1 = {fold8[4], fold8[5], fold8[6], fold8[7]};
            *(float4*)(msgrow + 0) = f0;
            *(float4*)(msgrow + 4) = f1;
        }
    } else if constexpr (VEC_OUT) {
        if (valid) {
#pragma unroll
            for (int w = 0; w < 16; w += 4) {
                float4 f0 = {mv0[w], mv0[w+1], mv0[w+2], mv0[w+3]};
                float4 f1 = {mv1[w], mv1[w+1], mv1[w+2], mv1[w+3]};
                float4 f2 = {mv2[w], mv2[w+1], mv2[w+2], mv2[w+3]};
                *(float4*)(msgrow + WMS + 0*16 + w) = f0;
                *(float4*)(msgrow + WMS + 1*16 + w) = f1;
                *(float4*)(msgrow + WMS + 2*16 + w) = f2;
            }
        }
    }
}

// ---------------------------------------------------------------- segmented sum (row-major msg, float4)
template<int W>
__global__ void __launch_bounds__(256) k_segsum(
    const float* __restrict__ msg, float* __restrict__ Y,
    const int* __restrict__ start, int p0, int p1, int first)
{
    constexpr int W4 = W/4;
    int idx = blockIdx.x*blockDim.x + threadIdx.x;
    if (idx >= NN*W4) return;
    int n = idx / W4;
    int c4 = idx - n*W4;
    int lo = start[n], hi = start[n+1];
    if (lo < p0) lo = p0;
    if (hi > p1) hi = p1;
    float4 s = {0.f, 0.f, 0.f, 0.f};
    if (lo < hi) {
        const float* q = msg + (size_t)(lo - p0)*W + c4*4;
        for (int p = lo; p < hi; ++p) {
            float4 v = *(const float4*)q;
            s.x += v.x; s.y += v.y; s.z += v.z; s.w += v.w;
            q += W;
        }
    }
    float* yp = Y + (size_t)n*W + c4*4;
    if (first) *(float4*)yp = s;
    else if (lo < hi) {
        float4 y = *(const float4*)yp;
        y.x += s.x; y.y += s.y; y.z += s.z; y.w += s.w;
        *(float4*)yp = y;
    }
}

// ---------------------------------------------------------------- node post + gate (in-place; Y row-major)
template<int SIN, int YSW, int WST, bool HASV>
__global__ void __launch_bounds__(256) k_post(
    float* __restrict__ xsv, float* __restrict__ xvv,
    const float* __restrict__ Y,
    const float* __restrict__ scs, const float* __restrict__ scv,
    const float* __restrict__ l2s,
    float s_sc, float s_l2s, float s_scv, float s_l2v)
{
    __shared__ float Lscs[SIN*48];
    __shared__ float Ll2s[YSW*48];
    __shared__ float Lscv[HASV ? 256 : 1];
    for (int i = threadIdx.x; i < SIN*48; i += blockDim.x) Lscs[i] = scs[i];
    for (int i = threadIdx.x; i < YSW*48; i += blockDim.x) Ll2s[i] = l2s[i];
    if constexpr (HASV)
        for (int i = threadIdx.x; i < 256; i += blockDim.x) Lscv[i] = scv[i];
    __syncthreads();
    int n = blockIdx.x*blockDim.x + threadIdx.x;
    if (n >= NN) return;
    const float* yrow = Y + (size_t)n*WST;
    float xr[SIN];
#pragma unroll
    for (int u = 0; u < SIN; ++u) xr[u] = xsv[n*48 + u];
    float yr[YSW];
#pragma unroll
    for (int t = 0; t < YSW; ++t) yr[t] = yrow[t]*ISNN;
    float os[48];
    const float A = C_S*s_sc, B = C_X*s_l2s;
#pragma unroll
    for (int j = 0; j < 48; ++j) {
        float a = 0.f, b = 0.f;
#pragma unroll
        for (int u = 0; u < SIN; ++u) a += xr[u]*Lscs[u*48 + j];
#pragma unroll
        for (int t = 0; t < YSW; ++t) b += yr[t]*Ll2s[t*48 + j];
        os[j] = A*a + B*b;
    }
#pragma unroll
    for (int u = 0; u < 32; ++u) xsv[n*48 + u] = siluf(os[u]);
    float gg[16];
#pragma unroll
    for (int t = 0; t < 16; ++t) gg[t] = sigmf(os[32 + t]);
    const float sc3 = ISNN*s_l2v*(HASV ? C_X : 1.0f);
    if constexpr (HASV) {
        float vr[48];
#pragma unroll
        for (int i = 0; i < 48; ++i) vr[i] = xvv[n*48 + i];
        const float Av = C_S*s_scv;
#pragma unroll
        for (int w = 0; w < 16; ++w) {
            float s0 = 0.f, s1 = 0.f, s2 = 0.f;
#pragma unroll
            for (int v = 0; v < 16; ++v) {
                float wt = Lscv[v*16 + w];
                s0 += vr[v*3+0]*wt; s1 += vr[v*3+1]*wt; s2 += vr[v*3+2]*wt;
            }
            xvv[n*48 + w*3 + 0] = (Av*s0 + sc3*yrow[YSW + 0*16 + w])*gg[w];
            xvv[n*48 + w*3 + 1] = (Av*s1 + sc3*yrow[YSW + 1*16 + w])*gg[w];
            xvv[n*48 + w*3 + 2] = (Av*s2 + sc3*yrow[YSW + 2*16 + w])*gg[w];
        }
    } else {
#pragma unroll
        for (int w = 0; w < 16; ++w) {
            xvv[n*48 + w*3 + 0] = sc3*yrow[YSW + 0*16 + w]*gg[w];
            xvv[n*48 + w*3 + 1] = sc3*yrow[YSW + 1*16 + w]*gg[w];
            xvv[n*48 + w*3 + 2] = sc3*yrow[YSW + 2*16 + w]*gg[w];
        }
    }
}

// ---------------------------------------------------------------- layer4 post + head
__global__ void __launch_bounds__(256) k_final(
    const float* __restrict__ xsv, const float* __restrict__ Y8,
    const float* __restrict__ scs,
    const float* __restrict__ Wh, const float* __restrict__ bh,
    float* __restrict__ out)
{
    __shared__ float Lscs[32*8];
    __shared__ float Lwh[24];
    __shared__ float Lbh[3];
    for (int i = threadIdx.x; i < 32*8; i += blockDim.x) Lscs[i] = scs[i];
    if (threadIdx.x < 24) Lwh[threadIdx.x] = Wh[threadIdx.x];
    if (threadIdx.x < 3)  Lbh[threadIdx.x] = bh[threadIdx.x];
    __syncthreads();
    int n = blockIdx.x*blockDim.x + threadIdx.x;
    if (n >= NN) return;
    float xr[32];
#pragma unroll
    for (int u = 0; u < 32; ++u) xr[u] = xsv[n*48 + u];
    const float CB = C_X*RS48*ISNN;
    float s8[8];
#pragma unroll
    for (int j = 0; j < 8; ++j) {
        float a = 0.f;
#pragma unroll
        for (int u = 0; u < 32; ++u) a += xr[u]*Lscs[u*8 + j];
        s8[j] = C_S*RS32*a + CB*Y8[n*8 + j];
    }
#pragma unroll
    for (int c = 0; c < 3; ++c) {
        float o = Lbh[c];
#pragma unroll
        for (int j = 0; j < 8; ++j) o += s8[j]*Lwh[j*3 + c];
        out[n*3 + c] = o;
    }
}

// ---------------------------------------------------------------- launcher
extern "C" void kernel_launch(void* const* d_in, const int* in_sizes, int n_in,
                              void* d_out, int out_size, void* d_ws, size_t ws_size,
                              hipStream_t stream)
{
    const float* pos       = (const float*)d_in[0];
    const float* onehot    = (const float*)d_in[1];
    const float* eattr     = (const float*)d_in[2];
    const float* W_embed   = (const float*)d_in[3];
    const float* b_embed   = (const float*)d_in[4];
    const float* l1_lin1_s = (const float*)d_in[5];
    const float* l1_sc_s   = (const float*)d_in[6];
    const float* l1_R1     = (const float*)d_in[7];
    const float* l1_R2     = (const float*)d_in[8];
    const float* l1_lin2_s = (const float*)d_in[9];
    const float* l1_lin2_v = (const float*)d_in[10];
    const float* l2_lin1_s = (const float*)d_in[11];
    const float* l2_lin1_v = (const float*)d_in[12];
    const float* l2_sc_s   = (const float*)d_in[13];
    const float* l2_sc_v   = (const float*)d_in[14];
    const float* l2_R1     = (const float*)d_in[15];
    const float* l2_R2     = (const float*)d_in[16];
    const float* l2_lin2_s = (const float*)d_in[17];
    const float* l2_lin2_v = (const float*)d_in[18];
    const float* l3_lin1_s = (const float*)d_in[19];
    const float* l3_lin1_v = (const float*)d_in[20];
    const float* l3_sc_s   = (const float*)d_in[21];
    const float* l3_sc_v   = (const float*)d_in[22];
    const float* l3_R1     = (const float*)d_in[23];
    const float* l3_R2     = (const float*)d_in[24];
    const float* l3_lin2_s = (const float*)d_in[25];
    const float* l3_lin2_v = (const float*)d_in[26];
    const float* l4_lin1_s = (const float*)d_in[27];
    const float* l4_lin1_v = (const float*)d_in[28];
    const float* l4_sc_s   = (const float*)d_in[29];
    const float* l4_R1     = (const float*)d_in[30];
    const float* l4_R2     = (const float*)d_in[31];
    const float* l4_lin2_s = (const float*)d_in[32];
    const float* W_head    = (const float*)d_in[33];
    const float* b_head    = (const float*)d_in[34];
    const int*   eidx      = (const int*)d_in[35];
    const int* srcv = eidx;
    const int* dstv = eidx + NE;

    float* ws = (float*)d_ws;
    size_t off = 0;
    float* XS     = ws + off; off += 48ull*NN;
    float* XV     = ws + off; off += 48ull*NN;
    float* XS1    = ws + off; off += 32ull*NN;
    float* XV1    = ws + off; off += 48ull*NN;
    float* Y      = ws + off; off += 96ull*NN;
    float* TAB    = ws + off; off += (size_t)TT*60*4;
    int*   start  = (int*)(ws + off); off += ((NN + 1 + 3) & ~3);
    int*   cursor = (int*)(ws + off); off += NN;
    int*   perm   = (int*)(ws + off); off += NE;
    int*   SRCg   = (int*)(ws + off); off += NE;
    int*   LIVEf  = (int*)(ws + off); off += NE;
    float* GEO    = ws + off; off += 8ull*NE;
    float* MSG    = ws + off;
    size_t totalFloats = ws_size/4;
    size_t msgCap = (totalFloats > off) ? (totalFloats - off) : 0;

    dim3 th(256), be((NE + 255)/256), bn((NN + 255)/256);

    long ECall;
    {
        long cap = (long)(msgCap/96) & ~255L;
        ECall = (cap >= NE) ? NE : cap;     // single chunk if workspace allows
        if (ECall < 4096) ECall = 4096;
    }

    // ---- live classify + dst sort + geometry pre-gather
    hipMemsetAsync(cursor, 0, NN*sizeof(int), stream);
    k_hist2<<<be, th, 0, stream>>>(pos, srcv, dstv, cursor, LIVEf);
    k_scan<<<1, 1024, 0, stream>>>(cursor, start);
    k_scatter2<<<be, th, 0, stream>>>(dstv, LIVEf, cursor, perm);
    k_geo<<<be, th, 0, stream>>>(pos, eattr, srcv, dstv, perm, start, SRCg, GEO);

    k_embed<<<(NN*64 + 255)/256, th, 0, stream>>>(onehot, W_embed, b_embed, XS);

    dim3 tb(512), gb(TT/8);

    // ---- layer 1 (S=16, V=0, WOUT=80; msg width 64)
    {
        k_pre<16,16,0><<<bn, th, 0, stream>>>(XS, nullptr, l1_lin1_s, nullptr, XS1, XV1, RS16, RS16);
        k_tab<80><<<gb, tb, 0, stream>>>(l1_R1, l1_R2, TAB);
        for (long c0 = 0; c0 < NE; c0 += ECall) {
            int p0 = (int)c0, p1 = (int)((c0 + ECall < NE) ? c0 + ECall : NE);
            dim3 ge(((p1-p0) + 255)/256);
            k_edge13<16,0,80,true,false,64,16><<<ge, th, 0, stream>>>(
                SRCg, GEO, XS1, XV1, TAB, l1_lin2_v, MSG, p0, p1, start);
            dim3 gs((NN*16 + 255)/256);
            k_segsum<64><<<gs, th, 0, stream>>>(MSG, Y, start, p0, p1, c0 == 0);
        }
        k_post<16,16,64,false><<<bn, th, 0, stream>>>(XS, XV, Y, l1_sc_s, nullptr, l1_lin2_s,
                                                      RS16, RS16, 0.f, RS16);
    }

    // ---- layers 2,3 (S=32, V=16, WOUT=240; msg width 96)
    const float* L2w[2][6] = {
        {l2_lin1_s, l2_lin1_v, l2_R1, l2_R2, l2_lin2_v, l2_lin2_s},
        {l3_lin1_s, l3_lin1_v, l3_R1, l3_R2, l3_lin2_v, l3_lin2_s}};
    const float* L2sc[2][2] = {{l2_sc_s, l2_sc_v}, {l3_sc_s, l3_sc_v}};
    for (int L = 0; L < 2; ++L) {
        k_pre<32,32,16><<<bn, th, 0, stream>>>(XS, XV, L2w[L][0], L2w[L][1], XS1, XV1, RS32, RS16);
        k_tab<240><<<gb, tb, 0, stream>>>(L2w[L][2], L2w[L][3], TAB);
        for (long c0 = 0; c0 < NE; c0 += ECall) {
            int p0 = (int)c0, p1 = (int)((c0 + ECall < NE) ? c0 + ECall : NE);
            dim3 ge(((p1-p0) + 255)/256);
            k_edge13<32,16,240,true,false,96,48><<<ge, th, 0, stream>>>(
                SRCg, GEO, XS1, XV1, TAB, L2w[L][4], MSG, p0, p1, start);
            dim3 gs((NN*24 + 255)/256);
            k_segsum<96><<<gs, th, 0, stream>>>(MSG, Y, start, p0, p1, c0 == 0);
        }
        k_post<32,48,96,true><<<bn, th, 0, stream>>>(XS, XV, Y, L2sc[L][0], L2sc[L][1], L2w[L][5],
                                                     RS32, RS48, RS16, RS48);
    }

    // ---- layer 4 (S=32, V=16, WOUT=144; lin2_s folded -> msg width 8)
    {
        k_pre<32,32,16><<<bn, th, 0, stream>>>(XS, XV, l4_lin1_s, l4_lin1_v, XS1, XV1, RS32, RS16);
        k_tab<144><<<gb, tb, 0, stream>>>(l4_R1, l4_R2, TAB);
        for (long c0 = 0; c0 < NE; c0 += ECall) {
            int p0 = (int)c0, p1 = (int)((c0 + ECall < NE) ? c0 + ECall : NE);
            dim3 ge(((p1-p0) + 255)/256);
            k_edge13<32,16,144,false,true,8,48><<<ge, th, 0, stream>>>(
                SRCg, GEO, XS1, XV1, TAB, l4_lin2_s, MSG, p0, p1, start);
            dim3 gs((NN*2 + 255)/256);
            k_segsum<8><<<gs, th, 0, stream>>>(MSG, Y, start, p0, p1, c0 == 0);
        }
        k_final<<<bn, th, 0, stream>>>(XS, Y, l4_sc_s, W_head, b_head, (float*)d_out);
    }
}